// Round 1
// baseline (316.208 us; speedup 1.0000x reference)
//
#include <hip/hip_runtime.h>
#include <math.h>

// out = relu( tile(pool2(x1),2) + tile(pool4(x2),4) + tile(pool8(x3),8)
//             + tile(pool16(x4),16) + ff )   all NCHW fp32, B=16, out 16x256x24x24.
//
// Round-4: occupancy + load-batching rework of the round-3 single kernel.
// rocprof on round-3: dur 115us, 1.6 TB/s (20% peak), VALUBusy 3%, Occupancy 26%,
// VGPR=32 -> latency-bound: grid of 768 blocks caps at 12/32 waves per CU and
// 32 VGPRs means ~1-2 float4 loads in flight per lane.
//
// Changes:
//  - Block footprint 12 -> 4 output columns: grid = 16*24*6 = 2304 blocks
//    (9 blocks/CU, 8 resident = 32 waves/CU = 100% wave slots).
//  - Every phase is exactly ONE task per thread (256 tasks/phase), no serial
//    3-iteration loops.
//  - Loads batched through explicit float4 v[N] arrays (up to 8 in flight,
//    32 data VGPRs) to cover ~900cy HBM latency; __launch_bounds__(256,8)
//    caps VGPR at 64 so 8 blocks/CU is guaranteed.
//  - LDS transposed to [col][ch] (3840 B/block): phase-E scalar reads are
//    same-bank-2-way at worst (free per m136), vs 8-way with [ch][col] float4.

namespace {

__device__ __forceinline__ float fmax4(const float4 v) {
  return fmaxf(fmaxf(v.x, v.y), fmaxf(v.z, v.w));
}

__global__ __launch_bounds__(256, 8) void fused_block(const float* __restrict__ x1,
                                                      const float* __restrict__ x2,
                                                      const float* __restrict__ x3,
                                                      const float* __restrict__ x4,
                                                      const float* __restrict__ ff,
                                                      float* __restrict__ out) {
  // Transposed pooled tiles: s*t[col][ch], col = 0..3 within this block's 4 output cols.
  __shared__ float s1t[4 * 128];
  __shared__ float s2t[4 * 64];
  __shared__ float s3t[4 * 32];
  __shared__ float s4t[4 * 16];

  const int blk  = blockIdx.x;      // 0..2303
  const int b    = blk / 144;       // batch
  const int rem  = blk % 144;
  const int oh   = rem / 6;         // output row 0..23
  const int quad = rem % 6;         // output cols quad*4 .. quad*4+3
  const int tid  = threadIdx.x;

  // ---- Phase A: x1 [16,128,48,48], K=2. task = ch(128) x pid(2).
  //      One float4 covers 2 windows; 2 row loads. ----
  {
    const int ch = tid >> 1, pid = tid & 1;
    const float* p = x1 + (size_t)b * 294912 + (size_t)ch * 2304
                        + oh * 96 + quad * 8 + pid * 4;
    const float4 a = *reinterpret_cast<const float4*>(p);
    const float4 c = *reinterpret_cast<const float4*>(p + 48);
    s1t[(pid * 2) * 128 + ch]     = fmaxf(fmaxf(a.x, a.y), fmaxf(c.x, c.y));
    s1t[(pid * 2 + 1) * 128 + ch] = fmaxf(fmaxf(a.z, a.w), fmaxf(c.z, c.w));
  }

  // ---- Phase B: x2 [16,64,96,96], K=4. task = ch(64) x ow(4); 4 row loads. ----
  {
    const int ch = tid >> 2, ow = tid & 3;
    const float* p = x2 + (size_t)b * 589824 + (size_t)ch * 9216
                        + oh * 384 + quad * 16 + ow * 4;
    float4 v[4];
#pragma unroll
    for (int r = 0; r < 4; ++r) v[r] = *reinterpret_cast<const float4*>(p + r * 96);
    float m = fmax4(v[0]);
#pragma unroll
    for (int r = 1; r < 4; ++r) m = fmaxf(m, fmax4(v[r]));
    s2t[ow * 64 + ch] = m;
  }

  // ---- Phase C: x3 [16,32,192,192], K=8. task = ch(32) x ow(4) x hf(2);
  //      2 lanes/window, 8 row loads each, shfl reduce. ----
  {
    const int ch = tid >> 3, ow = (tid >> 1) & 3, hf = tid & 1;
    const float* p = x3 + (size_t)b * 1179648 + (size_t)ch * 36864
                        + oh * 1536 + quad * 32 + ow * 8 + hf * 4;
    float4 v[8];
#pragma unroll
    for (int r = 0; r < 8; ++r) v[r] = *reinterpret_cast<const float4*>(p + r * 192);
    float m = fmax4(v[0]);
#pragma unroll
    for (int r = 1; r < 8; ++r) m = fmaxf(m, fmax4(v[r]));
    m = fmaxf(m, __shfl_xor(m, 1));
    if (hf == 0) s3t[ow * 32 + ch] = m;
  }

  // ---- Phase D: x4 [16,16,384,384], K=16. task = ch(16) x ow(4) x q(4);
  //      4 lanes/window, 16 row loads each in two batches of 8, shfl reduce. ----
  {
    const int ch = tid >> 4, ow = (tid >> 2) & 3, q = tid & 3;
    const float* p = x4 + (size_t)b * 2359296 + (size_t)ch * 147456
                        + oh * 6144 + quad * 64 + ow * 16 + q * 4;
    float m = -INFINITY;
#pragma unroll
    for (int h = 0; h < 2; ++h) {
      float4 v[8];
#pragma unroll
      for (int r = 0; r < 8; ++r)
        v[r] = *reinterpret_cast<const float4*>(p + (h * 8 + r) * 384);
#pragma unroll
      for (int r = 0; r < 8; ++r) m = fmaxf(m, fmax4(v[r]));
    }
    m = fmaxf(m, __shfl_xor(m, 1));
    m = fmaxf(m, __shfl_xor(m, 2));
    if (q == 0) s4t[ow * 16 + ch] = m;
  }

  __syncthreads();

  // ---- Phase E: combine. task = channel(256); float4 over this block's 4 cols. ----
  {
    const int c = tid;
    const size_t o = (size_t)b * 147456 + (size_t)c * 576 + oh * 24 + quad * 4;
    const float4 f = *reinterpret_cast<const float4*>(ff + o);
    const int c1 = c & 127, c2 = c & 63, c3 = c & 31, c4 = c & 15;
    float4 r;
    r.x = fmaxf(s1t[0 * 128 + c1] + s2t[0 * 64 + c2] + s3t[0 * 32 + c3] + s4t[0 * 16 + c4] + f.x, 0.0f);
    r.y = fmaxf(s1t[1 * 128 + c1] + s2t[1 * 64 + c2] + s3t[1 * 32 + c3] + s4t[1 * 16 + c4] + f.y, 0.0f);
    r.z = fmaxf(s1t[2 * 128 + c1] + s2t[2 * 64 + c2] + s3t[2 * 32 + c3] + s4t[2 * 16 + c4] + f.z, 0.0f);
    r.w = fmaxf(s1t[3 * 128 + c1] + s2t[3 * 64 + c2] + s3t[3 * 32 + c3] + s4t[3 * 16 + c4] + f.w, 0.0f);
    *reinterpret_cast<float4*>(out + o) = r;
  }
}

}  // namespace

extern "C" void kernel_launch(void* const* d_in, const int* in_sizes, int n_in,
                              void* d_out, int out_size, void* d_ws, size_t ws_size,
                              hipStream_t stream) {
  const float* x1 = (const float*)d_in[0];  // [16,128,48,48]
  const float* x2 = (const float*)d_in[1];  // [16,64,96,96]
  const float* x3 = (const float*)d_in[2];  // [16,32,192,192]
  const float* x4 = (const float*)d_in[3];  // [16,16,384,384]
  const float* ff = (const float*)d_in[4];  // [16,256,24,24]
  float* out = (float*)d_out;               // [16,256,24,24]
  (void)d_ws; (void)ws_size; (void)in_sizes; (void)n_in; (void)out_size;

  fused_block<<<2304, 256, 0, stream>>>(x1, x2, x3, x4, ff, out);
}